// Round 16
// baseline (217.994 us; speedup 1.0000x reference)
//
#include <hip/hip_runtime.h>

typedef unsigned short u16;
typedef unsigned char  u8;
typedef __attribute__((ext_vector_type(4))) float  f32x4;
typedef __attribute__((ext_vector_type(2))) float  f32x2;
typedef __attribute__((ext_vector_type(8))) short  bf16x8;
typedef __attribute__((ext_vector_type(8))) u16    u16x8;
typedef __attribute__((ext_vector_type(4))) float  float4v;

#define NVOC   50000
#define BSEG   4096
#define TOK_PER_SEG 32
#define ZSCALE 8.0f

__device__ __forceinline__ u16 f2b(float x){
  union { float f; unsigned u; } v; v.f = x;
  unsigned u = v.u;
  unsigned r = (u + 0x7fffu + ((u >> 16) & 1u)) >> 16;
  return (u16)r;
}
__device__ __forceinline__ u8 enc8(float x){
  int p = __builtin_amdgcn_cvt_pk_fp8_f32(x, x, 0, false);
  return (u8)(p & 0xff);
}
__device__ __forceinline__ void dec8(unsigned lo, unsigned hi, float* f){
  f32x2 a = __builtin_amdgcn_cvt_pk_f32_fp8(lo, false);
  f32x2 b = __builtin_amdgcn_cvt_pk_f32_fp8(lo, true);
  f32x2 c = __builtin_amdgcn_cvt_pk_f32_fp8(hi, false);
  f32x2 d = __builtin_amdgcn_cvt_pk_f32_fp8(hi, true);
  f[0]=a[0]; f[1]=a[1]; f[2]=b[0]; f[3]=b[1];
  f[4]=c[0]; f[5]=c[1]; f[6]=d[0]; f[7]=d[1];
}
__device__ __forceinline__ void gload_lds16(const void* g, void* l){
  __builtin_amdgcn_global_load_lds((const __attribute__((address_space(1))) void*)g,
                                   (__attribute__((address_space(3))) void*)l,
                                   16, 0, 0);
}

// ---------------- K0: prep (v = W1@W2, c = b1@W2+b2, Bt) + W_emb->bf16 ----------------
__global__ __launch_bounds__(256)
void prep_aconv_kernel(const float* __restrict__ W1, const float* __restrict__ b1,
                       const float* __restrict__ W2, const float* __restrict__ b2,
                       const float* __restrict__ conv_w, const float* __restrict__ W_emb,
                       float* __restrict__ v, float* __restrict__ cptr,
                       u16* __restrict__ Bt, u16* __restrict__ A)
{
  const int bid = blockIdx.x, tid = threadIdx.x;
  if (bid < 769){
    const int j = bid;
    const int lane = tid & 63, wave = tid >> 6;
    __shared__ float red[4];
    float p = (j < 768) ? W1[j*256 + tid] * W2[tid] : b1[tid] * W2[tid];
    #pragma unroll
    for (int off = 32; off; off >>= 1) p += __shfl_down(p, off);
    if (lane == 0) red[wave] = p;
    __syncthreads();
    if (tid == 0){
      float s = red[0] + red[1] + red[2] + red[3];
      if (j < 768) v[j] = s; else *cptr = s + b2[0];
    }
    if (j < 768){
      int k = j >> 8, o = j & 255;
      Bt[j*256 + tid] = f2b(conv_w[o*768 + tid*3 + k]);
    }
  } else {
    size_t idx = ((size_t)(bid - 769) * 256 + tid) * 8;
    if (idx >= (size_t)NVOC * 256) return;
    const float4v* p = (const float4v*)(W_emb + idx);
    float4v a = p[0], b = p[1];
    u16x8 r;
    r[0]=f2b(a[0]); r[1]=f2b(a[1]); r[2]=f2b(a[2]); r[3]=f2b(a[3]);
    r[4]=f2b(b[0]); r[5]=f2b(b[1]); r[6]=f2b(b[2]); r[7]=f2b(b[3]);
    *(u16x8*)(A + idx) = r;
  }
}

// ---------------- K1: GEMM  Z[v][k][o] = W_emb[v,:] @ conv_w[o,:,k] (fp8 out) --------
__global__ __launch_bounds__(256, 2)
void gemm_kernel(const u16* __restrict__ A, const u16* __restrict__ Bt,
                 u8* __restrict__ Z)
{
  const int m0 = blockIdx.x * 128, n0 = blockIdx.y * 128;
  const int tid = threadIdx.x, lane = tid & 63, wave = tid >> 6;
  const int wm = wave >> 1, wn = wave & 1;

  __shared__ __align__(16) u16 As[2][128*64];
  __shared__ __align__(16) u16 Bs[2][128*64];

  f32x4 acc[4][4] = {};

  auto stage = [&](int buf, int ks){
    const int kk = ks * 64;
    #pragma unroll
    for (int i = 0; i < 4; i++){
      int c = i*256 + wave*64 + lane;
      int row = c >> 3, ch = c & 7;
      int gch = ch ^ (row & 7);
      gload_lds16(A + (size_t)(m0 + row)*256 + kk + gch*8,
                  &As[buf][(i*256 + wave*64)*8]);
    }
    #pragma unroll
    for (int i = 0; i < 4; i++){
      int c = i*256 + wave*64 + lane;
      int row = c >> 3, ch = c & 7;
      int gch = ch ^ (row & 7);
      gload_lds16(Bt + (size_t)(n0 + row)*256 + kk + gch*8,
                  &Bs[buf][(i*256 + wave*64)*8]);
    }
  };

  stage(0, 0);
  __syncthreads();
  for (int ks = 0; ks < 4; ++ks){
    const int buf = ks & 1;
    if (ks < 3) stage(buf ^ 1, ks + 1);
    #pragma unroll
    for (int k2 = 0; k2 < 2; ++k2){
      bf16x8 af[4], bfv[4];
      #pragma unroll
      for (int mi = 0; mi < 4; mi++){
        int rr = wm*64 + mi*16 + (lane & 15);
        int gg = k2*4 + (lane >> 4);
        int ch = gg ^ (rr & 7);
        af[mi] = *(const bf16x8*)&As[buf][(rr*8 + ch)*8];
      }
      #pragma unroll
      for (int nj = 0; nj < 4; nj++){
        int rr = wn*64 + nj*16 + (lane & 15);
        int gg = k2*4 + (lane >> 4);
        int ch = gg ^ (rr & 7);
        bfv[nj] = *(const bf16x8*)&Bs[buf][(rr*8 + ch)*8];
      }
      #pragma unroll
      for (int mi = 0; mi < 4; mi++)
        #pragma unroll
        for (int nj = 0; nj < 4; nj++)
          acc[mi][nj] = __builtin_amdgcn_mfma_f32_16x16x32_bf16(af[mi], bfv[nj], acc[mi][nj], 0, 0, 0);
    }
    __syncthreads();
  }

  #pragma unroll
  for (int mi = 0; mi < 4; mi++){
    #pragma unroll
    for (int nj = 0; nj < 4; nj++){
      int j = n0 + wn*64 + nj*16 + (lane & 15);
      int k = j >> 8, o = j & 255;
      #pragma unroll
      for (int qq = 0; qq < 4; qq++){
        int vr = m0 + wm*64 + mi*16 + (lane >> 4)*4 + qq;
        if (vr < NVOC)
          Z[((size_t)vr * 3 + k) * 256 + o] = enc8(acc[mi][nj][qq] * ZSCALE);
      }
    }
  }
}

// ---------------- K2: NE gather/max/mean -> logitN  (idempotent; run 3x to time) -----
__global__ __launch_bounds__(256)
void ne_kernel(const int* __restrict__ NE_ids, const u8* __restrict__ Z,
               const float* __restrict__ conv_b, const float* __restrict__ v,
               float* __restrict__ logitN)
{
  const int seg = blockIdx.x;
  const int tid = threadIdx.x, lane = tid & 63, wave = tid >> 6;
  const int ni = tid >> 5, oc = tid & 31;
  __shared__ int ids[64];
  __shared__ float red_s[4];
  if (tid < 64) ids[tid] = NE_ids[seg*64 + tid];
  __syncthreads();

  const int* id = &ids[ni*8];
  const size_t cb = (size_t)oc * 8;

  uint2 z0[7], z1[8], z2[7];
  #pragma unroll
  for (int l = 0; l < 8; l++)
    z1[l] = *(const uint2*)(Z + (size_t)id[l]*768 + 256 + cb);
  #pragma unroll
  for (int l = 0; l < 7; l++){
    z0[l] = *(const uint2*)(Z + (size_t)id[l]*768 +       cb);
    z2[l] = *(const uint2*)(Z + (size_t)id[l+1]*768 + 512 + cb);
  }

  float maxv[8];
  #pragma unroll
  for (int j = 0; j < 8; j++) maxv[j] = -1e30f;
  #pragma unroll
  for (int l = 0; l < 8; l++){
    float d1[8], d0[8], d2[8];
    dec8(z1[l].x, z1[l].y, d1);
    if (l > 0) dec8(z0[l-1].x, z0[l-1].y, d0);
    if (l < 7) dec8(z2[l].x, z2[l].y, d2);
    #pragma unroll
    for (int j = 0; j < 8; j++){
      float s = d1[j];
      if (l > 0) s += d0[j];
      if (l < 7) s += d2[j];
      maxv[j] = fmaxf(maxv[j], s);
    }
  }

  float part = 0.f;
  #pragma unroll
  for (int j = 0; j < 8; j++){
    float vj = v[512 + oc*8 + j];
    part += maxv[j] * (0.125f / ZSCALE) * vj;
    if (tid < 32) part += conv_b[oc*8 + j] * vj;
  }
  #pragma unroll
  for (int off = 32; off; off >>= 1) part += __shfl_down(part, off);
  if (lane == 0) red_s[wave] = part;
  __syncthreads();
  if (tid == 0) logitN[seg] = red_s[0] + red_s[1] + red_s[2] + red_s[3];
}

// ---------------- K3: attention pool (dense lane mapping) + final sigmoid ----------------
__global__ __launch_bounds__(256)
void attn_final_kernel(const float* __restrict__ h, const float* __restrict__ Watt,
                       const float* __restrict__ v, const float* __restrict__ logitN,
                       const float* __restrict__ cptr, float* __restrict__ out)
{
  const int s = blockIdx.x;
  const int tid = threadIdx.x, lane = tid & 63, wave = tid >> 6;
  __shared__ float pl_s[4], den_s[4];

  const float* gh = h + (size_t)s * TOK_PER_SEG * 512 + (size_t)wave * 8 * 512;
  const int d0 = lane * 4;

  float wr[8], vv[8];
  #pragma unroll
  for (int j = 0; j < 4; j++){
    wr[j]   = Watt[d0 + j];       vv[j]   = v[d0 + j];
    wr[4+j] = Watt[256 + d0 + j]; vv[4+j] = v[256 + d0 + j];
  }

  float o[8] = {0,0,0,0,0,0,0,0};
  float den = 0.f;
  #pragma unroll
  for (int t = 0; t < 8; t++){
    float4v h0 = *(const float4v*)(gh + t*512 + d0);
    float4v h1 = *(const float4v*)(gh + t*512 + 256 + d0);
    float aa = h0[0]*wr[0] + h0[1]*wr[1] + h0[2]*wr[2] + h0[3]*wr[3]
             + h1[0]*wr[4] + h1[1]*wr[5] + h1[2]*wr[6] + h1[3]*wr[7];
    #pragma unroll
    for (int off = 1; off < 64; off <<= 1) aa += __shfl_xor(aa, off);
    float w = __expf(aa);
    den += w;
    #pragma unroll
    for (int j = 0; j < 4; j++) o[j]   += w * h0[j];
    #pragma unroll
    for (int j = 0; j < 4; j++) o[j+4] += w * h1[j];
  }
  float pl = 0.f;
  #pragma unroll
  for (int j = 0; j < 8; j++) pl += o[j] * vv[j];
  #pragma unroll
  for (int off = 32; off; off >>= 1) pl += __shfl_down(pl, off);
  if (lane == 0){ pl_s[wave] = pl; den_s[wave] = den; }
  __syncthreads();
  if (tid == 0){
    float num = pl_s[0] + pl_s[1] + pl_s[2] + pl_s[3];
    float dn  = den_s[0] + den_s[1] + den_s[2] + den_s[3];
    float logit = num / dn + logitN[s] + cptr[0];
    out[s] = 1.f / (1.f + __expf(-logit));
  }
}

extern "C" void kernel_launch(void* const* d_in, const int* in_sizes, int n_in,
                              void* d_out, int out_size, void* d_ws, size_t ws_size,
                              hipStream_t stream)
{
  const float* h      = (const float*)d_in[0];
  const float* W_emb  = (const float*)d_in[1];
  const float* W_att  = (const float*)d_in[2];
  const float* conv_w = (const float*)d_in[4];
  const float* conv_b = (const float*)d_in[5];
  const float* W1     = (const float*)d_in[6];
  const float* b1     = (const float*)d_in[7];
  const float* W2     = (const float*)d_in[8];
  const float* b2     = (const float*)d_in[9];
  const int*   NE_ids = (const int*)d_in[10];
  float* out = (float*)d_out;

  char* ws = (char*)d_ws;
  float* v_f    = (float*)(ws + 0);                 // 768 f32
  float* c_f    = (float*)(ws + 3072);              // 1 f32
  float* logitN = (float*)(ws + 20480);             // 4096 f32
  u16*   Bt     = (u16*)(ws + 36864);               // 768*256 bf16
  u16*   Abf    = (u16*)(ws + 430080);              // 50048*256 bf16
  u8*    Z      = (u8*)(ws + 26054656ULL);          // 50000*3*256 fp8, [v][3][256]

  prep_aconv_kernel<<<769 + 6250, 256, 0, stream>>>(W1, b1, W2, b2, conv_w, W_emb,
                                                    v_f, c_f, Bt, Abf);
  gemm_kernel<<<dim3(391, 6), 256, 0, stream>>>(Abf, Bt, Z);
  // INSTRUMENTATION: ne_kernel is idempotent; run 3x. ne_true = (dur - 145.6)/2.
  ne_kernel<<<4096, 256, 0, stream>>>(NE_ids, Z, conv_b, v_f, logitN);
  ne_kernel<<<4096, 256, 0, stream>>>(NE_ids, Z, conv_b, v_f, logitN);
  ne_kernel<<<4096, 256, 0, stream>>>(NE_ids, Z, conv_b, v_f, logitN);
  attn_final_kernel<<<4096, 256, 0, stream>>>(h, W_att, v_f, logitN, c_f, out);
}

// Round 17
// 136.042 us; speedup vs baseline: 1.6024x; 1.6024x over previous
//
#include <hip/hip_runtime.h>

typedef unsigned short u16;
typedef unsigned char  u8;
typedef __attribute__((ext_vector_type(4))) float  f32x4;
typedef __attribute__((ext_vector_type(2))) float  f32x2;
typedef __attribute__((ext_vector_type(8))) short  bf16x8;
typedef __attribute__((ext_vector_type(8))) u16    u16x8;
typedef __attribute__((ext_vector_type(4))) float  float4v;

#define NVOC   50000
#define BSEG   4096
#define TOK_PER_SEG 32
#define ZSCALE 8.0f

__device__ __forceinline__ u16 f2b(float x){
  union { float f; unsigned u; } v; v.f = x;
  unsigned u = v.u;
  unsigned r = (u + 0x7fffu + ((u >> 16) & 1u)) >> 16;
  return (u16)r;
}
__device__ __forceinline__ u8 enc8(float x){
  int p = __builtin_amdgcn_cvt_pk_fp8_f32(x, x, 0, false);
  return (u8)(p & 0xff);
}
__device__ __forceinline__ void dec8(unsigned lo, unsigned hi, float* f){
  f32x2 a = __builtin_amdgcn_cvt_pk_f32_fp8(lo, false);
  f32x2 b = __builtin_amdgcn_cvt_pk_f32_fp8(lo, true);
  f32x2 c = __builtin_amdgcn_cvt_pk_f32_fp8(hi, false);
  f32x2 d = __builtin_amdgcn_cvt_pk_f32_fp8(hi, true);
  f[0]=a[0]; f[1]=a[1]; f[2]=b[0]; f[3]=b[1];
  f[4]=c[0]; f[5]=c[1]; f[6]=d[0]; f[7]=d[1];
}
__device__ __forceinline__ void gload_lds16(const void* g, void* l){
  __builtin_amdgcn_global_load_lds((const __attribute__((address_space(1))) void*)g,
                                   (__attribute__((address_space(3))) void*)l,
                                   16, 0, 0);
}

// ---------------- K0: prep (v = W1@W2, c = b1@W2+b2, Bt) ----------------
__global__ __launch_bounds__(256)
void prep_kernel(const float* __restrict__ W1, const float* __restrict__ b1,
                 const float* __restrict__ W2, const float* __restrict__ b2,
                 const float* __restrict__ conv_w,
                 float* __restrict__ v, float* __restrict__ cptr,
                 u16* __restrict__ Bt)
{
  const int j = blockIdx.x, tid = threadIdx.x;
  const int lane = tid & 63, wave = tid >> 6;
  __shared__ float red[4];
  float p = (j < 768) ? W1[j*256 + tid] * W2[tid] : b1[tid] * W2[tid];
  #pragma unroll
  for (int off = 32; off; off >>= 1) p += __shfl_down(p, off);
  if (lane == 0) red[wave] = p;
  __syncthreads();
  if (tid == 0){
    float s = red[0] + red[1] + red[2] + red[3];
    if (j < 768) v[j] = s; else *cptr = s + b2[0];
  }
  if (j < 768){
    int k = j >> 8, o = j & 255;
    Bt[j*256 + tid] = f2b(conv_w[o*768 + tid*3 + k]);
  }
}

// ---------------- K1: m-major GEMM — A staged ONCE from W_emb f32 ----------------
// Block = 128 A-rows. As[128][256] bf16 (64KB, persistent, swizzled via reg-staging).
// Loops 6 n-blocks x 4 k-steps; Bs[128][64] (16KB) re-staged from L2-resident Bt.
// Z[v][k][o] fp8, scaled x8.
__global__ __launch_bounds__(256, 2)
void gemm_m_kernel(const float* __restrict__ W_emb, const u16* __restrict__ Bt,
                   u8* __restrict__ Z)
{
  __shared__ __align__(16) u16 As[128*256];   // 64 KB
  __shared__ __align__(16) u16 Bs[128*64];    // 16 KB
  const int m0 = blockIdx.x * 128;
  const int tid = threadIdx.x, lane = tid & 63, wave = tid >> 6;
  const int wm = wave >> 1, wn = wave & 1;

  // ---- stage A once: 16 chunks (16B bf16) per thread, f32->bf16, swizzled write ----
  #pragma unroll
  for (int i = 0; i < 16; i++){
    int c = i*256 + tid;
    int row = c >> 5, ch = c & 31;          // 32 chunks of 8 bf16 per 256-wide row
    int gr = m0 + row;
    u16x8 rv = {0,0,0,0,0,0,0,0};
    if (gr < NVOC){
      const float4v* p = (const float4v*)(W_emb + (size_t)gr*256 + ch*8);
      float4v a = p[0], b = p[1];
      rv[0]=f2b(a[0]); rv[1]=f2b(a[1]); rv[2]=f2b(a[2]); rv[3]=f2b(a[3]);
      rv[4]=f2b(b[0]); rv[5]=f2b(b[1]); rv[6]=f2b(b[2]); rv[7]=f2b(b[3]);
    }
    int chs = ch ^ (row & 7);               // XOR low 3 bits (write side)
    *(u16x8*)&As[(row*32 + chs)*8] = rv;
  }
  __syncthreads();

  for (int n0 = 0; n0 < 6; n0++){
    f32x4 acc[4][4] = {};
    for (int ks = 0; ks < 4; ks++){
      // stage Bs[128][64] from Bt rows [n0*128, n0*128+128), k-window ks*64
      #pragma unroll
      for (int i = 0; i < 4; i++){
        int c = i*256 + tid;
        int row = c >> 3, ch = c & 7;
        int gch = ch ^ (row & 7);
        gload_lds16(Bt + (size_t)(n0*128 + row)*256 + ks*64 + gch*8,
                    &Bs[(i*256 + wave*64)*8]);
      }
      __syncthreads();
      #pragma unroll
      for (int k2 = 0; k2 < 2; ++k2){
        bf16x8 af[4], bfv[4];
        #pragma unroll
        for (int mi = 0; mi < 4; mi++){
          int rr = wm*64 + mi*16 + (lane & 15);
          int chunk = ks*8 + k2*4 + (lane >> 4);
          int chs = chunk ^ (rr & 7);       // XOR low 3 bits (read side, matches write)
          af[mi] = *(const bf16x8*)&As[(rr*32 + chs)*8];
        }
        #pragma unroll
        for (int nj = 0; nj < 4; nj++){
          int rr = wn*64 + nj*16 + (lane & 15);
          int ch = (k2*4 + (lane >> 4)) ^ (rr & 7);
          bfv[nj] = *(const bf16x8*)&Bs[(rr*8 + ch)*8];
        }
        #pragma unroll
        for (int mi = 0; mi < 4; mi++)
          #pragma unroll
          for (int nj = 0; nj < 4; nj++)
            acc[mi][nj] = __builtin_amdgcn_mfma_f32_16x16x32_bf16(af[mi], bfv[nj], acc[mi][nj], 0, 0, 0);
      }
      __syncthreads();
    }
    // epilogue for this n-block
    #pragma unroll
    for (int mi = 0; mi < 4; mi++){
      #pragma unroll
      for (int nj = 0; nj < 4; nj++){
        int j = n0*128 + wn*64 + nj*16 + (lane & 15);
        int k = j >> 8, o = j & 255;
        #pragma unroll
        for (int qq = 0; qq < 4; qq++){
          int vr = m0 + wm*64 + mi*16 + (lane >> 4)*4 + qq;
          if (vr < NVOC)
            Z[((size_t)vr * 3 + k) * 256 + o] = enc8(acc[mi][nj][qq] * ZSCALE);
        }
      }
    }
  }
}

// ---------------- K2: NE gather/max/mean -> logitN ----------------
__global__ __launch_bounds__(256)
void ne_kernel(const int* __restrict__ NE_ids, const u8* __restrict__ Z,
               const float* __restrict__ conv_b, const float* __restrict__ v,
               float* __restrict__ logitN)
{
  const int seg = blockIdx.x;
  const int tid = threadIdx.x, lane = tid & 63, wave = tid >> 6;
  const int ni = tid >> 5, oc = tid & 31;
  __shared__ int ids[64];
  __shared__ float red_s[4];
  if (tid < 64) ids[tid] = NE_ids[seg*64 + tid];
  __syncthreads();

  const int* id = &ids[ni*8];
  const size_t cb = (size_t)oc * 8;

  uint2 z0[7], z1[8], z2[7];
  #pragma unroll
  for (int l = 0; l < 8; l++)
    z1[l] = *(const uint2*)(Z + (size_t)id[l]*768 + 256 + cb);
  #pragma unroll
  for (int l = 0; l < 7; l++){
    z0[l] = *(const uint2*)(Z + (size_t)id[l]*768 +       cb);
    z2[l] = *(const uint2*)(Z + (size_t)id[l+1]*768 + 512 + cb);
  }

  float maxv[8];
  #pragma unroll
  for (int j = 0; j < 8; j++) maxv[j] = -1e30f;
  #pragma unroll
  for (int l = 0; l < 8; l++){
    float d1[8], d0[8], d2[8];
    dec8(z1[l].x, z1[l].y, d1);
    if (l > 0) dec8(z0[l-1].x, z0[l-1].y, d0);
    if (l < 7) dec8(z2[l].x, z2[l].y, d2);
    #pragma unroll
    for (int j = 0; j < 8; j++){
      float s = d1[j];
      if (l > 0) s += d0[j];
      if (l < 7) s += d2[j];
      maxv[j] = fmaxf(maxv[j], s);
    }
  }

  float part = 0.f;
  #pragma unroll
  for (int j = 0; j < 8; j++){
    float vj = v[512 + oc*8 + j];
    part += maxv[j] * (0.125f / ZSCALE) * vj;
    if (tid < 32) part += conv_b[oc*8 + j] * vj;
  }
  #pragma unroll
  for (int off = 32; off; off >>= 1) part += __shfl_down(part, off);
  if (lane == 0) red_s[wave] = part;
  __syncthreads();
  if (tid == 0) logitN[seg] = red_s[0] + red_s[1] + red_s[2] + red_s[3];
}

// ---------------- K3: attention pool (dense lane mapping) + final sigmoid ----------------
__global__ __launch_bounds__(256)
void attn_final_kernel(const float* __restrict__ h, const float* __restrict__ Watt,
                       const float* __restrict__ v, const float* __restrict__ logitN,
                       const float* __restrict__ cptr, float* __restrict__ out)
{
  const int s = blockIdx.x;
  const int tid = threadIdx.x, lane = tid & 63, wave = tid >> 6;
  __shared__ float pl_s[4], den_s[4];

  const float* gh = h + (size_t)s * TOK_PER_SEG * 512 + (size_t)wave * 8 * 512;
  const int d0 = lane * 4;

  float wr[8], vv[8];
  #pragma unroll
  for (int j = 0; j < 4; j++){
    wr[j]   = Watt[d0 + j];       vv[j]   = v[d0 + j];
    wr[4+j] = Watt[256 + d0 + j]; vv[4+j] = v[256 + d0 + j];
  }

  float o[8] = {0,0,0,0,0,0,0,0};
  float den = 0.f;
  #pragma unroll
  for (int t = 0; t < 8; t++){
    float4v h0 = *(const float4v*)(gh + t*512 + d0);
    float4v h1 = *(const float4v*)(gh + t*512 + 256 + d0);
    float aa = h0[0]*wr[0] + h0[1]*wr[1] + h0[2]*wr[2] + h0[3]*wr[3]
             + h1[0]*wr[4] + h1[1]*wr[5] + h1[2]*wr[6] + h1[7-3]*wr[7];
    // NOTE: h1[7-3] == h1[4]? -- guard against typo: use explicit form below instead
    aa = h0[0]*wr[0] + h0[1]*wr[1] + h0[2]*wr[2] + h0[3]*wr[3]
       + h1[0]*wr[4] + h1[1]*wr[5] + h1[2]*wr[6] + h1[3]*wr[7];
    #pragma unroll
    for (int off = 1; off < 64; off <<= 1) aa += __shfl_xor(aa, off);
    float w = __expf(aa);
    den += w;
    #pragma unroll
    for (int j = 0; j < 4; j++) o[j]   += w * h0[j];
    #pragma unroll
    for (int j = 0; j < 4; j++) o[j+4] += w * h1[j];
  }
  float pl = 0.f;
  #pragma unroll
  for (int j = 0; j < 8; j++) pl += o[j] * vv[j];
  #pragma unroll
  for (int off = 32; off; off >>= 1) pl += __shfl_down(pl, off);
  if (lane == 0){ pl_s[wave] = pl; den_s[wave] = den; }
  __syncthreads();
  if (tid == 0){
    float num = pl_s[0] + pl_s[1] + pl_s[2] + pl_s[3];
    float dn  = den_s[0] + den_s[1] + den_s[2] + den_s[3];
    float logit = num / dn + logitN[s] + cptr[0];
    out[s] = 1.f / (1.f + __expf(-logit));
  }
}

extern "C" void kernel_launch(void* const* d_in, const int* in_sizes, int n_in,
                              void* d_out, int out_size, void* d_ws, size_t ws_size,
                              hipStream_t stream)
{
  const float* h      = (const float*)d_in[0];
  const float* W_emb  = (const float*)d_in[1];
  const float* W_att  = (const float*)d_in[2];
  const float* conv_w = (const float*)d_in[4];
  const float* conv_b = (const float*)d_in[5];
  const float* W1     = (const float*)d_in[6];
  const float* b1     = (const float*)d_in[7];
  const float* W2     = (const float*)d_in[8];
  const float* b2     = (const float*)d_in[9];
  const int*   NE_ids = (const int*)d_in[10];
  float* out = (float*)d_out;

  char* ws = (char*)d_ws;
  float* v_f    = (float*)(ws + 0);                 // 768 f32
  float* c_f    = (float*)(ws + 3072);              // 1 f32
  float* logitN = (float*)(ws + 20480);             // 4096 f32
  u16*   Bt     = (u16*)(ws + 36864);               // 768*256 bf16
  u8*    Z      = (u8*)(ws + 26054656ULL);          // 50000*3*256 fp8, [v][3][256]

  prep_kernel<<<769, 256, 0, stream>>>(W1, b1, W2, b2, conv_w, v_f, c_f, Bt);
  gemm_m_kernel<<<391, 256, 0, stream>>>(W_emb, Bt, Z);
  ne_kernel<<<4096, 256, 0, stream>>>(NE_ids, Z, conv_b, v_f, logitN);
  attn_final_kernel<<<4096, 256, 0, stream>>>(h, W_att, v_f, logitN, c_f, out);
}